// Round 2
// baseline (655.500 us; speedup 1.0000x reference)
//
#include <hip/hip_runtime.h>

// RGCN block: B=512, C=256, R=8, N=81 (9x9), fp32 in/out, bf16 MFMA compute.
//
// out_h[b,n,d] = sum_r (adj[b,r] @ h[b]) @ W[r],  h[b][m][c] = x[b][c][m]
// pre = out_h^T + x ; BN(train, biased) over (B,N) per channel ; *gamma+beta ; relu

#define B_SZ 512
#define C_SZ 256
#define R_SZ 8
#define N_SZ 81
#define TH 512         // threads per block in main kernel

typedef short bf16x8 __attribute__((ext_vector_type(8)));
typedef float f32x4 __attribute__((ext_vector_type(4)));

__device__ __forceinline__ unsigned short f2bf(float f) {
    union { float f; unsigned u; } v; v.f = f;
    unsigned r = v.u + 0x7FFFu + ((v.u >> 16) & 1u);   // RNE
    return (unsigned short)(r >> 16);
}

// msgs layout: 96 rows x 256 cols bf16, row stride 512 B, XOR-swizzled 16B slots.
__device__ __forceinline__ int msg_addr(int row, int colbyte) {
    int s = (row ^ (row >> 3)) & 7;
    return row * 512 + (colbyte ^ (s << 4));
}

// ---- kernel 0: weight (R,C,C) fp32 -> WT[r][d][c] bf16 ----
__global__ void prep_wt(const float* __restrict__ w, unsigned short* __restrict__ wt) {
    int i = blockIdx.x * blockDim.x + threadIdx.x;
    if (i >= R_SZ * C_SZ * C_SZ) return;
    int r = i >> 16;
    int d = (i >> 8) & 255;
    int c = i & 255;
    wt[i] = f2bf(w[(r * C_SZ + c) * C_SZ + d]);   // wt layout [r][d][c]
}

// ---- kernel 1: fused RGCN per batch ----
// grid 512 blocks x 512 threads (8 waves as 2 row x 4 col); 2 blocks/CU.
__launch_bounds__(TH, 4)
__global__ void rgcn_main(const float* __restrict__ x,
                          const float* __restrict__ adj,
                          const unsigned short* __restrict__ wt,
                          float* __restrict__ out,
                          float* __restrict__ psum) {
    __shared__ __align__(16) unsigned char msgsB[96 * 512];   // 49152 B (also epilogue buf)
    __shared__ unsigned short adjs[96][104];                  // 19968 B

    const int b    = blockIdx.x;
    const int tid  = threadIdx.x;
    const int lane = tid & 63;
    const int wave = tid >> 6;
    const int wrow = wave >> 2;     // 0..1  -> 48 output rows each
    const int wcol = wave & 3;      // 0..3  -> 64 output cols each
    const int lr   = lane & 15;     // fragment row (A) / col (B,D)
    const int lk   = lane >> 4;     // k-chunk 0..3

    const float* xb   = x + (size_t)b * C_SZ * N_SZ;
    const float* adjb = adj + (size_t)b * R_SZ * N_SZ * N_SZ;

    // ---- hoist stage-1 B fragments (h) into registers: reused for all 8 relations ----
    bf16x8 hfr[3][4];   // [kk][j]
#pragma unroll
    for (int kk = 0; kk < 3; ++kk) {
#pragma unroll
        for (int j = 0; j < 4; ++j) {
            int c = wcol * 64 + j * 16 + lr;
            int m0 = kk * 32 + lk * 8;
#pragma unroll
            for (int e = 0; e < 8; ++e) {
                int m = m0 + e;
                float v = (m < N_SZ) ? xb[c * N_SZ + m] : 0.f;
                hfr[kk][j][e] = (short)f2bf(v);
            }
        }
    }

    // ---- zero adjs pads, then load adj[0] ----
    for (int i = tid; i < 96 * 104; i += TH) ((unsigned short*)adjs)[i] = 0;
    __syncthreads();
    for (int i = tid; i < N_SZ * N_SZ; i += TH) {
        int n = i / N_SZ, m = i - n * N_SZ;
        adjs[n][m] = f2bf(adjb[i]);
    }
    __syncthreads();

    f32x4 acc[3][4];
    const f32x4 vzero = {0.f, 0.f, 0.f, 0.f};
#pragma unroll
    for (int i = 0; i < 3; ++i)
#pragma unroll
        for (int j = 0; j < 4; ++j) acc[i][j] = vzero;

    for (int r = 0; r < R_SZ; ++r) {
        // ---- prefetch adj[r+1] into registers (hidden under stage1+stage2) ----
        float pf[13];
        if (r < R_SZ - 1) {
            const float* an = adjb + (r + 1) * (N_SZ * N_SZ);
#pragma unroll
            for (int u = 0; u < 13; ++u) {
                int i = tid + u * TH;
                if (i < N_SZ * N_SZ) pf[u] = an[i];
            }
        }

        // ---- stage 1: msg = adj_r @ h   (96 x 256, K=96) ----
        f32x4 macc[3][4];
#pragma unroll
        for (int i = 0; i < 3; ++i)
#pragma unroll
            for (int j = 0; j < 4; ++j) macc[i][j] = vzero;

#pragma unroll
        for (int kk = 0; kk < 3; ++kk) {
            bf16x8 afr[3];
#pragma unroll
            for (int i = 0; i < 3; ++i) {
                int row = wrow * 48 + i * 16 + lr;
                afr[i] = *(const bf16x8*)&adjs[row][kk * 32 + lk * 8];
            }
#pragma unroll
            for (int i = 0; i < 3; ++i)
#pragma unroll
                for (int j = 0; j < 4; ++j)
                    macc[i][j] = __builtin_amdgcn_mfma_f32_16x16x32_bf16(afr[i], hfr[kk][j], macc[i][j], 0, 0, 0);
        }

        // write msg to LDS bf16, swizzled (D layout: col=lane&15, row=(lane>>4)*4+q)
#pragma unroll
        for (int i = 0; i < 3; ++i) {
            int rowb = wrow * 48 + i * 16 + lk * 4;
#pragma unroll
            for (int j = 0; j < 4; ++j) {
                int colb = (wcol * 64 + j * 16 + lr) * 2;
#pragma unroll
                for (int q = 0; q < 4; ++q)
                    *(unsigned short*)(msgsB + msg_addr(rowb + q, colb)) = f2bf(macc[i][j][q]);
            }
        }
        __syncthreads();   // msg ready; all stage-1 adjs reads complete

        // ---- stage 2: acc += msg @ W_r  (K=256), B streamed from L2-resident WT ----
        const unsigned short* wr = wt + r * (C_SZ * C_SZ);
#pragma unroll
        for (int kk = 0; kk < 8; ++kk) {
            bf16x8 afr[3], bfr[4];
#pragma unroll
            for (int i = 0; i < 3; ++i) {
                int row = wrow * 48 + i * 16 + lr;
                afr[i] = *(const bf16x8*)(msgsB + msg_addr(row, kk * 64 + lk * 16));
            }
#pragma unroll
            for (int j = 0; j < 4; ++j) {
                int col = wcol * 64 + j * 16 + lr;               // channel d
                bfr[j] = *(const bf16x8*)&wr[col * 256 + kk * 32 + lk * 8];
            }
#pragma unroll
            for (int i = 0; i < 3; ++i)
#pragma unroll
                for (int j = 0; j < 4; ++j)
                    acc[i][j] = __builtin_amdgcn_mfma_f32_16x16x32_bf16(afr[i], bfr[j], acc[i][j], 0, 0, 0);
        }

        // ---- write prefetched adj[r+1] to LDS (safe: stage1 readers passed barrier) ----
        if (r < R_SZ - 1) {
#pragma unroll
            for (int u = 0; u < 13; ++u) {
                int i = tid + u * TH;
                if (i < N_SZ * N_SZ) {
                    int n = i / N_SZ, m = i - n * N_SZ;
                    adjs[n][m] = f2bf(pf[u]);
                }
            }
        }
        __syncthreads();   // adj[r+1] ready; stage-2 msgs reads complete
    }

    // ---- epilogue: stage acc through LDS (2 halves), coalesced pre/out/BN sums ----
    float* buf = (float*)msgsB;          // [128][84] fp32 = 43008 B
    float* outb = out + (size_t)b * C_SZ * N_SZ;
#pragma unroll 1
    for (int half = 0; half < 2; ++half) {
        if ((wcol >> 1) == half) {
#pragma unroll
            for (int i = 0; i < 3; ++i) {
#pragma unroll
                for (int j = 0; j < 4; ++j) {
                    int d_rel = (wcol & 1) * 64 + j * 16 + lr;
#pragma unroll
                    for (int q = 0; q < 4; ++q) {
                        int n = wrow * 48 + i * 16 + lk * 4 + q;
                        if (n < N_SZ) buf[d_rel * 84 + n] = acc[i][j][q];
                    }
                }
            }
        }
        __syncthreads();
        // each wave owns 16 whole channels: coalesced read/add/write + reduce
#pragma unroll 1
        for (int t = 0; t < 16; ++t) {
            int d_rel = wave * 16 + t;
            int d = half * 128 + d_rel;
            float s1 = 0.f, s2 = 0.f;
            float pre0 = buf[d_rel * 84 + lane] + xb[d * N_SZ + lane];
            // lane 0..63 all < 81
            outb[d * N_SZ + lane] = pre0;
            s1 += pre0; s2 += pre0 * pre0;
            int n1 = lane + 64;
            if (n1 < N_SZ) {
                float pre1 = buf[d_rel * 84 + n1] + xb[d * N_SZ + n1];
                outb[d * N_SZ + n1] = pre1;
                s1 += pre1; s2 += pre1 * pre1;
            }
#pragma unroll
            for (int off = 32; off > 0; off >>= 1) {
                s1 += __shfl_down(s1, off);
                s2 += __shfl_down(s2, off);
            }
            if (lane == 0) {
                psum[(size_t)b * 256 + d] = s1;
                psum[(size_t)B_SZ * 256 + (size_t)b * 256 + d] = s2;
            }
        }
        __syncthreads();   // buf free before next half
    }
}

// ---- kernel 2: reduce per-block partials -> mean, rstd per channel ----
__global__ void bn_stats(const float* __restrict__ psum, float* __restrict__ mr) {
    int c = threadIdx.x;   // 256 threads, 1 block
    float s1 = 0.f, s2 = 0.f;
    for (int b = 0; b < B_SZ; ++b) {
        s1 += psum[(size_t)b * 256 + c];
        s2 += psum[(size_t)B_SZ * 256 + (size_t)b * 256 + c];
    }
    const float inv = 1.0f / (float)(B_SZ * N_SZ);
    float mean = s1 * inv;
    float var = s2 * inv - mean * mean;
    mr[c] = mean;
    mr[256 + c] = rsqrtf(var + 1e-5f);
}

// ---- kernel 3: normalize + gamma/beta + relu, in place on out ----
__global__ void bn_apply(float* __restrict__ out, const float* __restrict__ mr,
                         const float* __restrict__ gamma, const float* __restrict__ beta) {
    const int total = B_SZ * C_SZ * N_SZ;
    for (int i = blockIdx.x * blockDim.x + threadIdx.x; i < total;
         i += gridDim.x * blockDim.x) {
        int c = (i / N_SZ) & 255;
        float v = out[i];
        v = (v - mr[c]) * mr[256 + c] * gamma[c] + beta[c];
        out[i] = v > 0.f ? v : 0.f;
    }
}

extern "C" void kernel_launch(void* const* d_in, const int* in_sizes, int n_in,
                              void* d_out, int out_size, void* d_ws, size_t ws_size,
                              hipStream_t stream) {
    const float* x     = (const float*)d_in[0];
    const float* adj   = (const float*)d_in[1];
    const float* w     = (const float*)d_in[2];
    const float* gamma = (const float*)d_in[3];
    const float* beta  = (const float*)d_in[4];
    float* out = (float*)d_out;

    // workspace layout
    unsigned short* wt = (unsigned short*)d_ws;                              // 1 MB
    char* p = (char*)d_ws + (size_t)R_SZ * C_SZ * C_SZ * 2;
    float* psum = (float*)p;                                                 // 1 MB
    float* mr = (float*)(p + (size_t)2 * B_SZ * 256 * 4);                    // 2 KB

    prep_wt<<<(R_SZ * C_SZ * C_SZ + 255) / 256, 256, 0, stream>>>(w, wt);
    rgcn_main<<<B_SZ, TH, 0, stream>>>(x, adj, wt, out, psum);
    bn_stats<<<1, 256, 0, stream>>>(psum, mr);
    bn_apply<<<2048, 256, 0, stream>>>(out, mr, gamma, beta);
}

// Round 3
// 293.870 us; speedup vs baseline: 2.2306x; 2.2306x over previous
//
#include <hip/hip_runtime.h>

// RGCN block: B=512, C=256, R=8, N=81 (9x9), fp32 in/out, bf16 MFMA compute.
// out_h[b,n,d] = sum_r (adj[b,r] @ h[b]) @ W[r],  h[b][m][c] = x[b][c][m]
// pre = out_h^T + x ; BN(train, biased) over (B,N) per channel ; *gamma+beta ; relu
//
// Grid: 1024 blocks = (b, n-half). Each block: 48 output rows x 256 channels.
// 8 waves split by columns (32 each). acc/macc = 24 regs each -> fits 128-reg
// budget (4 waves/SIMD, 2 blocks/CU) without spilling.

#define B_SZ 512
#define C_SZ 256
#define R_SZ 8
#define N_SZ 81
#define TH 512

typedef short bf16x8 __attribute__((ext_vector_type(8)));
typedef float f32x4 __attribute__((ext_vector_type(4)));

__device__ __forceinline__ unsigned short f2bf(float f) {
    union { float f; unsigned u; } v; v.f = f;
    unsigned r = v.u + 0x7FFFu + ((v.u >> 16) & 1u);   // RNE
    return (unsigned short)(r >> 16);
}

// LDS partition (single byte array, manual offsets; 16B-overflow reads stay in-alloc)
#define HT_OFF   0                       // hT[256][88] bf16 = 45056 B
#define ADJ_OFF  45056                   // adj[48][88] bf16 = 8448 B
#define MSG_OFF  53504                   // msg 48 rows x 512 B swizzled = 24576 B
#define SMEM_SZ  (78080 + 32)

// msg: row stride 512 B, 16B slots XOR-swizzled by row
__device__ __forceinline__ int msg_addr(int row, int colbyte) {
    int s = (row ^ (row >> 3)) & 7;
    return MSG_OFF + row * 512 + (colbyte ^ (s << 4));
}

// ---- kernel 0: weight (R,C,C) fp32 -> WT[r][d][c] bf16 ----
__global__ void prep_wt(const float* __restrict__ w, unsigned short* __restrict__ wt) {
    int i = blockIdx.x * blockDim.x + threadIdx.x;
    if (i >= R_SZ * C_SZ * C_SZ) return;
    int r = i >> 16;
    int d = (i >> 8) & 255;
    int c = i & 255;
    wt[i] = f2bf(w[(r * C_SZ + c) * C_SZ + d]);
}

// ---- kernel 1: fused RGCN, one block per (batch, n-half) ----
__launch_bounds__(TH, 4)
__global__ void rgcn_main(const float* __restrict__ x,
                          const float* __restrict__ adj,
                          const unsigned short* __restrict__ wt,
                          float* __restrict__ out,
                          float* __restrict__ psum) {
    __shared__ __align__(16) unsigned char smem[SMEM_SZ];
    unsigned short* hT   = (unsigned short*)(smem + HT_OFF);    // [c][88]
    unsigned short* adjs = (unsigned short*)(smem + ADJ_OFF);   // [n_loc][88]

    // XCD co-location: halves of the same batch land on the same XCD
    const int bid  = blockIdx.x;
    const int xcd  = bid & 7;
    const int slot = bid >> 3;            // 0..127
    const int b    = xcd * 64 + (slot >> 1);
    const int half = slot & 1;
    const int n0   = half * 48;

    const int tid  = threadIdx.x;
    const int lane = tid & 63;
    const int wave = tid >> 6;            // 0..7, column-split (32 cols each)
    const int lr   = lane & 15;
    const int lk   = lane >> 4;

    const float* xb   = x + (size_t)b * C_SZ * N_SZ;
    const float* adjb = adj + ((size_t)b * R_SZ * N_SZ + n0) * N_SZ;
    const int cnt = half ? (33 * N_SZ) : (48 * N_SZ);   // valid adj elems per relation

    // ---- prefetch adj(r=0) ----
    float pf[8];
#pragma unroll
    for (int u = 0; u < 8; ++u) {
        int i2 = tid + u * TH;
        pf[u] = (i2 < cnt) ? adjb[i2] : 0.f;
    }

    // ---- hT init (zero pad m 81..87), adjs zero ----
    for (int i = tid; i < 256 * 88; i += TH) {
        int c = i / 88, m = i - c * 88;
        hT[i] = (m < N_SZ) ? f2bf(xb[c * N_SZ + m]) : (unsigned short)0;
    }
    for (int i = tid; i < 48 * 88; i += TH) adjs[i] = 0;
    __syncthreads();
#pragma unroll
    for (int u = 0; u < 8; ++u) {
        int i2 = tid + u * TH;
        if (i2 < cnt) {
            int n = i2 / N_SZ, m = i2 - n * N_SZ;
            adjs[n * 88 + m] = f2bf(pf[u]);
        }
    }
    __syncthreads();

    const f32x4 vzero = {0.f, 0.f, 0.f, 0.f};
    const bf16x8 bz = {0, 0, 0, 0, 0, 0, 0, 0};
    f32x4 acc[3][2];
#pragma unroll
    for (int i = 0; i < 3; ++i)
#pragma unroll
        for (int j = 0; j < 2; ++j) acc[i][j] = vzero;

    const int colbase = wave * 32;        // this wave's 32 columns

    for (int r = 0; r < R_SZ; ++r) {
        // prefetch adj(r+1) into regs; latency hides under stage1
        if (r < R_SZ - 1) {
            const float* an = adjb + (r + 1) * (N_SZ * N_SZ);
#pragma unroll
            for (int u = 0; u < 8; ++u) {
                int i2 = tid + u * TH;
                pf[u] = (i2 < cnt) ? an[i2] : 0.f;
            }
        }

        // ---- stage 1: msg[48][256] = adj_half @ h  (K=96, m 88..95 masked) ----
        f32x4 macc[3][2];
#pragma unroll
        for (int i = 0; i < 3; ++i)
#pragma unroll
            for (int j = 0; j < 2; ++j) macc[i][j] = vzero;

#pragma unroll
        for (int kk = 0; kk < 3; ++kk) {
            const int kb = kk * 64 + lk * 16;    // byte offset within 176-B row
            bf16x8 afr[3], bfr[2];
#pragma unroll
            for (int i = 0; i < 3; ++i) {
                const unsigned char* p = (const unsigned char*)adjs + (i * 16 + lr) * 176 + kb;
                afr[i] = *(const bf16x8*)p;
            }
#pragma unroll
            for (int j = 0; j < 2; ++j) {
                const unsigned char* p = (const unsigned char*)hT + (colbase + j * 16 + lr) * 176 + kb;
                bfr[j] = *(const bf16x8*)p;
            }
            if (kk == 2 && lk == 3) {            // m 88..95: out of K range
#pragma unroll
                for (int i = 0; i < 3; ++i) afr[i] = bz;
#pragma unroll
                for (int j = 0; j < 2; ++j) bfr[j] = bz;
            }
#pragma unroll
            for (int i = 0; i < 3; ++i)
#pragma unroll
                for (int j = 0; j < 2; ++j)
                    macc[i][j] = __builtin_amdgcn_mfma_f32_16x16x32_bf16(afr[i], bfr[j], macc[i][j], 0, 0, 0);
        }
        __syncthreads();   // barrier A: adjs/msg readers done

        // write msg (D: col=lr-based, rows lk*4+q), swizzled
#pragma unroll
        for (int i = 0; i < 3; ++i) {
            int rowb = i * 16 + lk * 4;
#pragma unroll
            for (int j = 0; j < 2; ++j) {
                int colb = (colbase + j * 16 + lr) * 2;
#pragma unroll
                for (int q = 0; q < 4; ++q)
                    *(unsigned short*)(smem + msg_addr(rowb + q, colb)) = f2bf(macc[i][j][q]);
            }
        }
        // write prefetched adj(r+1)
        if (r < R_SZ - 1) {
#pragma unroll
            for (int u = 0; u < 8; ++u) {
                int i2 = tid + u * TH;
                if (i2 < cnt) {
                    int n = i2 / N_SZ, m = i2 - n * N_SZ;
                    adjs[n * 88 + m] = f2bf(pf[u]);
                }
            }
        }
        __syncthreads();   // barrier B: msg + adj ready

        // ---- stage 2: acc += msg @ W_r  (K=256), W from L2-resident wt ----
        const unsigned short* wr = wt + r * (C_SZ * C_SZ);
#pragma unroll
        for (int kk = 0; kk < 8; ++kk) {
            bf16x8 afr[3], bfr[2];
#pragma unroll
            for (int i = 0; i < 3; ++i)
                afr[i] = *(const bf16x8*)(smem + msg_addr(i * 16 + lr, kk * 64 + lk * 16));
#pragma unroll
            for (int j = 0; j < 2; ++j) {
                int d = colbase + j * 16 + lr;
                bfr[j] = *(const bf16x8*)&wr[d * 256 + kk * 32 + lk * 8];
            }
#pragma unroll
            for (int i = 0; i < 3; ++i)
#pragma unroll
                for (int j = 0; j < 2; ++j)
                    acc[i][j] = __builtin_amdgcn_mfma_f32_16x16x32_bf16(afr[i], bfr[j], acc[i][j], 0, 0, 0);
        }
    }

    // ---- epilogue: pre = acc + x, store, BN partials (register-direct, no atomics) ----
    float* outb = out + (size_t)b * C_SZ * N_SZ;
    float s1[2] = {0.f, 0.f}, s2[2] = {0.f, 0.f};
#pragma unroll
    for (int j = 0; j < 2; ++j) {
        int d = colbase + j * 16 + lr;
#pragma unroll
        for (int i = 0; i < 3; ++i) {
            int nb = n0 + i * 16 + lk * 4;
#pragma unroll
            for (int q = 0; q < 4; ++q) {
                int n = nb + q;
                if (n < N_SZ) {
                    float pre = acc[i][j][q] + xb[d * N_SZ + n];
                    outb[d * N_SZ + n] = pre;
                    s1[j] += pre;
                    s2[j] += pre * pre;
                }
            }
        }
    }
    const int bh = b * 2 + half;          // 0..1023
#pragma unroll
    for (int j = 0; j < 2; ++j) {
        s1[j] += __shfl_down(s1[j], 32);  s1[j] += __shfl_down(s1[j], 16);
        s2[j] += __shfl_down(s2[j], 32);  s2[j] += __shfl_down(s2[j], 16);
    }
    if (lane < 16) {
#pragma unroll
        for (int j = 0; j < 2; ++j) {
            int d = colbase + j * 16 + lane;
            psum[(size_t)d * 1024 + bh] = s1[j];
            psum[(size_t)C_SZ * 1024 + (size_t)d * 1024 + bh] = s2[j];
        }
    }
}

// ---- kernel 2: reduce partials -> scale/shift per channel ----
__global__ void bn_stats(const float* __restrict__ psum,
                         const float* __restrict__ gamma, const float* __restrict__ beta,
                         float* __restrict__ mr) {
    int c = blockIdx.x;      // 256 blocks x 64 threads
    int t = threadIdx.x;
    float a = 0.f, s = 0.f;
    for (int k = t; k < 1024; k += 64) {
        a += psum[(size_t)c * 1024 + k];
        s += psum[(size_t)C_SZ * 1024 + (size_t)c * 1024 + k];
    }
#pragma unroll
    for (int off = 32; off > 0; off >>= 1) {
        a += __shfl_down(a, off);
        s += __shfl_down(s, off);
    }
    if (t == 0) {
        const float inv = 1.0f / (float)(B_SZ * N_SZ);
        float mean = a * inv;
        float var = s * inv - mean * mean;
        float rstd = rsqrtf(var + 1e-5f);
        float scale = rstd * gamma[c];
        mr[c] = scale;
        mr[256 + c] = beta[c] - mean * scale;
    }
}

// ---- kernel 3: v = relu(v*scale[c] + shift[c]), float4 ----
__global__ void bn_apply(float* __restrict__ out, const float* __restrict__ mr) {
    const int total4 = (B_SZ * C_SZ * N_SZ) / 4;   // 10616832 / 4
    f32x4* o4 = (f32x4*)out;
    for (int i = blockIdx.x * blockDim.x + threadIdx.x; i < total4;
         i += gridDim.x * blockDim.x) {
        f32x4 v = o4[i];
        int e0 = i * 4;
#pragma unroll
        for (int k = 0; k < 4; ++k) {
            int c = ((e0 + k) / N_SZ) & 255;
            float t = v[k] * mr[c] + mr[256 + c];
            v[k] = t > 0.f ? t : 0.f;
        }
        o4[i] = v;
    }
}

extern "C" void kernel_launch(void* const* d_in, const int* in_sizes, int n_in,
                              void* d_out, int out_size, void* d_ws, size_t ws_size,
                              hipStream_t stream) {
    const float* x     = (const float*)d_in[0];
    const float* adj   = (const float*)d_in[1];
    const float* w     = (const float*)d_in[2];
    const float* gamma = (const float*)d_in[3];
    const float* beta  = (const float*)d_in[4];
    float* out = (float*)d_out;

    // workspace: wt 1MB | psum 2MB | mr 2KB
    unsigned short* wt = (unsigned short*)d_ws;
    char* p = (char*)d_ws + (size_t)R_SZ * C_SZ * C_SZ * 2;
    float* psum = (float*)p;
    float* mr = (float*)(p + (size_t)2 * 1024 * C_SZ * 4);

    prep_wt<<<(R_SZ * C_SZ * C_SZ + 255) / 256, 256, 0, stream>>>(w, wt);
    rgcn_main<<<1024, TH, 0, stream>>>(x, adj, wt, out, psum);
    bn_stats<<<C_SZ, 64, 0, stream>>>(psum, gamma, beta, mr);
    bn_apply<<<2048, 256, 0, stream>>>(out, mr);
}

// Round 5
// 235.470 us; speedup vs baseline: 2.7838x; 1.2480x over previous
//
#include <hip/hip_runtime.h>

// RGCN block: B=512, C=256, R=8, N=81 (9x9), fp32 in/out, bf16 MFMA compute.
// Transposed formulation: msgT[c][n] = h^T @ adj^T ; out^T[d][n] = W^T @ msg.
// Grid: 1024 blocks = (b, n-half of 48 rows). 8 waves, each 32 d x 48 n output.

#define B_SZ 512
#define C_SZ 256
#define R_SZ 8
#define N_SZ 81
#define TH 512

typedef short bf16x8 __attribute__((ext_vector_type(8)));
typedef float f32x4 __attribute__((ext_vector_type(4)));

__device__ __forceinline__ unsigned short f2bf(float f) {
    union { float f; unsigned u; } v; v.f = f;
    unsigned r = v.u + 0x7FFFu + ((v.u >> 16) & 1u);   // RNE
    return (unsigned short)(r >> 16);
}

// pack 4 f32 -> 4 bf16 in one u64, explicit order: v[0] lowest address
__device__ __forceinline__ unsigned long long pack4bf(f32x4 v) {
    unsigned long long r;
    r  = (unsigned long long)f2bf(v[0]);
    r |= (unsigned long long)f2bf(v[1]) << 16;
    r |= (unsigned long long)f2bf(v[2]) << 32;
    r |= (unsigned long long)f2bf(v[3]) << 48;
    return r;
}

// LDS: adjs [48][88] bf16 = 8448 B ; msg 48 rows x 512 B (XOR-swizzled 16B slots)
#define ADJ_OFF 0
#define MSG_OFF 8448
#define SMEM_SZ (8448 + 48 * 512 + 32)

__device__ __forceinline__ int msg_addr(int n, int cbyte) {
    int s = (n ^ (n >> 3)) & 7;
    return MSG_OFF + n * 512 + (cbyte ^ (s << 4));
}

// ---- kernel 0: weight (R,C,C) fp32 -> WT[r][d][c] bf16 ----
__global__ void prep_wt(const float* __restrict__ w, unsigned short* __restrict__ wt) {
    int i = blockIdx.x * blockDim.x + threadIdx.x;
    if (i >= R_SZ * C_SZ * C_SZ) return;
    int r = i >> 16;
    int d = (i >> 8) & 255;
    int c = i & 255;
    wt[i] = f2bf(w[(r * C_SZ + c) * C_SZ + d]);
}

// ---- kernel 1: fused RGCN, one block per (batch, n-half) ----
__launch_bounds__(TH, 4)
__global__ void rgcn_main(const float* __restrict__ x,
                          const float* __restrict__ adj,
                          const unsigned short* __restrict__ wt,
                          float* __restrict__ out,
                          float* __restrict__ psum) {
    __shared__ __align__(16) unsigned char smem[SMEM_SZ];
    unsigned short* adjs = (unsigned short*)(smem + ADJ_OFF);   // [n_loc][88]

    // XCD co-location (1024 % 8 == 0 -> bijective)
    const int bid  = blockIdx.x;
    const int xcd  = bid & 7;
    const int slot = bid >> 3;            // 0..127
    const int b    = xcd * 64 + (slot >> 1);
    const int half = slot & 1;
    const int n0   = half * 48;
    const int nvalid = half ? 33 : 48;
    const int cnt  = nvalid * N_SZ;

    const int tid  = threadIdx.x;
    const int lane = tid & 63;
    const int wave = tid >> 6;            // 0..7
    const int lr   = lane & 15;
    const int lk   = lane >> 4;
    const int cb   = wave * 32;           // this wave's 32 c rows (stage1) / d rows (stage2)

    const float* xb   = x + (size_t)b * C_SZ * N_SZ;
    const float* adjb = adj + ((size_t)b * R_SZ * N_SZ + n0) * N_SZ;

    // ---- h fragments in registers, relation-invariant. A-frag: row c, k=m.
    // m >= 81 zeroed at build => stage-1 K-pad contributions are exactly zero.
    bf16x8 hfr[3][2];
#pragma unroll
    for (int kk = 0; kk < 3; ++kk) {
#pragma unroll
        for (int jc = 0; jc < 2; ++jc) {
            int c = cb + jc * 16 + lr;
            const float* src = xb + c * N_SZ;
#pragma unroll
            for (int e = 0; e < 8; ++e) {
                int m = kk * 32 + lk * 8 + e;
                hfr[kk][jc][e] = (m < N_SZ) ? (short)f2bf(src[m]) : (short)0;
            }
        }
    }

    // ---- zero adjs (pads m>=81 and rows n>=nvalid stay zero forever) ----
    for (int i = tid; i < (48 * 88) / 2; i += TH) ((unsigned*)adjs)[i] = 0;

    // ---- adj(r=0): load regs ----
    float pf[8];
#pragma unroll
    for (int u = 0; u < 8; ++u) {
        int i2 = tid + u * TH;
        pf[u] = (i2 < cnt) ? adjb[i2] : 0.f;
    }
    __syncthreads();   // zero-init done before value stores
#pragma unroll
    for (int u = 0; u < 8; ++u) {
        int i2 = tid + u * TH;
        if (i2 < cnt) {
            int n = i2 / N_SZ, m = i2 - n * N_SZ;
            adjs[n * 88 + m] = f2bf(pf[u]);
        }
    }
    __syncthreads();

    const f32x4 vzero = {0.f, 0.f, 0.f, 0.f};
    f32x4 acc[2][3];
#pragma unroll
    for (int jd = 0; jd < 2; ++jd)
#pragma unroll
        for (int jn = 0; jn < 3; ++jn) acc[jd][jn] = vzero;

    for (int r = 0; r < R_SZ; ++r) {
        // prefetch adj(r+1)
        if (r < R_SZ - 1) {
            const float* an = adjb + (r + 1) * (N_SZ * N_SZ);
#pragma unroll
            for (int u = 0; u < 8; ++u) {
                int i2 = tid + u * TH;
                pf[u] = (i2 < cnt) ? an[i2] : 0.f;
            }
        }

        // ---- stage 1: msgT[c][n] ; A=h rows c (regs), B=adj rows n (LDS) ----
        f32x4 macc[2][3];
#pragma unroll
        for (int jc = 0; jc < 2; ++jc)
#pragma unroll
            for (int jn = 0; jn < 3; ++jn) macc[jc][jn] = vzero;

#pragma unroll
        for (int kk = 0; kk < 3; ++kk) {
            bf16x8 bfr[3];
#pragma unroll
            for (int jn = 0; jn < 3; ++jn)
                bfr[jn] = *(const bf16x8*)&adjs[(jn * 16 + lr) * 88 + kk * 32 + lk * 8];
#pragma unroll
            for (int jc = 0; jc < 2; ++jc)
#pragma unroll
                for (int jn = 0; jn < 3; ++jn)
                    macc[jc][jn] = __builtin_amdgcn_mfma_f32_16x16x32_bf16(hfr[kk][jc], bfr[jn], macc[jc][jn], 0, 0, 0);
        }

        // ---- issue first wt batch early (kk 0..1): latency hides under barrier ----
        const unsigned short* wr = wt + r * (C_SZ * C_SZ);
        bf16x8 wA[2][2], wB[2][2];   // [dk][jd]
#pragma unroll
        for (int dk = 0; dk < 2; ++dk)
#pragma unroll
            for (int jd = 0; jd < 2; ++jd)
                wA[dk][jd] = *(const bf16x8*)&wr[(cb + jd * 16 + lr) * 256 + dk * 32 + lk * 8];

        __syncthreads();   // A: stage1 adj reads + prev stage2 msg reads done

        // write msg[n][c]: lane holds 4 consecutive c for one n -> one b64 each
#pragma unroll
        for (int jc = 0; jc < 2; ++jc) {
#pragma unroll
            for (int jn = 0; jn < 3; ++jn) {
                int n = jn * 16 + lr;
                int cbyte = (cb + jc * 16 + lk * 4) * 2;
                *(unsigned long long*)(smem + msg_addr(n, cbyte)) = pack4bf(macc[jc][jn]);
            }
        }
        // write adj(r+1)
        if (r < R_SZ - 1) {
#pragma unroll
            for (int u = 0; u < 8; ++u) {
                int i2 = tid + u * TH;
                if (i2 < cnt) {
                    int n = i2 / N_SZ, m = i2 - n * N_SZ;
                    adjs[n * 88 + m] = f2bf(pf[u]);
                }
            }
        }
        __syncthreads();   // B: msg + adj(r+1) ready

        // ---- stage 2: out^T += W^T @ msg (K=256), wt double-buffered in regs ----
        auto do2 = [&](bf16x8 (&wc)[2][2], bf16x8 (&wn)[2][2], int kk0, bool load) {
            if (load) {
#pragma unroll
                for (int dk = 0; dk < 2; ++dk)
#pragma unroll
                    for (int jd = 0; jd < 2; ++jd)
                        wn[dk][jd] = *(const bf16x8*)&wr[(cb + jd * 16 + lr) * 256 + (kk0 + 2 + dk) * 32 + lk * 8];
            }
#pragma unroll
            for (int dk = 0; dk < 2; ++dk) {
                int kk = kk0 + dk;
                bf16x8 bfr[3];
#pragma unroll
                for (int jn = 0; jn < 3; ++jn)
                    bfr[jn] = *(const bf16x8*)(smem + msg_addr(jn * 16 + lr, kk * 64 + lk * 16));
#pragma unroll
                for (int jd = 0; jd < 2; ++jd)
#pragma unroll
                    for (int jn = 0; jn < 3; ++jn)
                        acc[jd][jn] = __builtin_amdgcn_mfma_f32_16x16x32_bf16(wc[dk][jd], bfr[jn], acc[jd][jn], 0, 0, 0);
            }
        };
        do2(wA, wB, 0, true);
        do2(wB, wA, 2, true);
        do2(wA, wB, 4, true);
        do2(wB, wA, 6, false);
    }

    // ---- epilogue: pre = out^T + x ; n-contiguous coalesced stores ; BN partials ----
    float* outb = out + (size_t)b * C_SZ * N_SZ;
    const int bh = b * 2 + half;
#pragma unroll
    for (int jd = 0; jd < 2; ++jd) {
        float s1[4] = {0.f, 0.f, 0.f, 0.f};
        float s2[4] = {0.f, 0.f, 0.f, 0.f};
#pragma unroll
        for (int jn = 0; jn < 3; ++jn) {
            int nloc = jn * 16 + lr;
            bool ok = nloc < nvalid;
            int n = n0 + nloc;
#pragma unroll
            for (int q = 0; q < 4; ++q) {
                int d = cb + jd * 16 + lk * 4 + q;
                if (ok) {
                    float pre = acc[jd][jn][q] + xb[d * N_SZ + n];
                    outb[d * N_SZ + n] = pre;
                    s1[q] += pre;
                    s2[q] += pre * pre;
                }
            }
        }
        // reduce over the 16 lr lanes (stay within 16-lane groups)
#pragma unroll
        for (int q = 0; q < 4; ++q) {
#pragma unroll
            for (int msk = 8; msk > 0; msk >>= 1) {
                s1[q] += __shfl_xor(s1[q], msk);
                s2[q] += __shfl_xor(s2[q], msk);
            }
        }
        if (lr == 0) {
#pragma unroll
            for (int q = 0; q < 4; ++q) {
                int d = cb + jd * 16 + lk * 4 + q;
                psum[(size_t)d * 1024 + bh] = s1[q];
                psum[(size_t)C_SZ * 1024 + (size_t)d * 1024 + bh] = s2[q];
            }
        }
    }
}

// ---- kernel 2: reduce partials -> scale/shift per channel ----
__global__ void bn_stats(const float* __restrict__ psum,
                         const float* __restrict__ gamma, const float* __restrict__ beta,
                         float* __restrict__ mr) {
    int c = blockIdx.x;      // 256 blocks x 64 threads
    int t = threadIdx.x;
    float a = 0.f, s = 0.f;
    for (int k = t; k < 1024; k += 64) {
        a += psum[(size_t)c * 1024 + k];
        s += psum[(size_t)C_SZ * 1024 + (size_t)c * 1024 + k];
    }
#pragma unroll
    for (int off = 32; off > 0; off >>= 1) {
        a += __shfl_down(a, off);
        s += __shfl_down(s, off);
    }
    if (t == 0) {
        const float inv = 1.0f / (float)(B_SZ * N_SZ);
        float mean = a * inv;
        float var = s * inv - mean * mean;
        float rstd = rsqrtf(var + 1e-5f);
        float scale = rstd * gamma[c];
        mr[c] = scale;
        mr[256 + c] = beta[c] - mean * scale;
    }
}

// ---- kernel 3: v = relu(v*scale[c] + shift[c]), float4 ----
__global__ void bn_apply(float* __restrict__ out, const float* __restrict__ mr) {
    const int total4 = (B_SZ * C_SZ * N_SZ) / 4;
    f32x4* o4 = (f32x4*)out;
    for (int i = blockIdx.x * blockDim.x + threadIdx.x; i < total4;
         i += gridDim.x * blockDim.x) {
        f32x4 v = o4[i];
        int e0 = i * 4;
#pragma unroll
        for (int k = 0; k < 4; ++k) {
            int c = ((e0 + k) / N_SZ) & 255;
            float t = v[k] * mr[c] + mr[256 + c];
            v[k] = t > 0.f ? t : 0.f;
        }
        o4[i] = v;
    }
}

extern "C" void kernel_launch(void* const* d_in, const int* in_sizes, int n_in,
                              void* d_out, int out_size, void* d_ws, size_t ws_size,
                              hipStream_t stream) {
    const float* x     = (const float*)d_in[0];
    const float* adj   = (const float*)d_in[1];
    const float* w     = (const float*)d_in[2];
    const float* gamma = (const float*)d_in[3];
    const float* beta  = (const float*)d_in[4];
    float* out = (float*)d_out;

    // workspace: wt 1MB | psum 2MB | mr 2KB
    unsigned short* wt = (unsigned short*)d_ws;
    char* p = (char*)d_ws + (size_t)R_SZ * C_SZ * C_SZ * 2;
    float* psum = (float*)p;
    float* mr = (float*)(p + (size_t)2 * 1024 * C_SZ * 4);

    prep_wt<<<(R_SZ * C_SZ * C_SZ + 255) / 256, 256, 0, stream>>>(w, wt);
    rgcn_main<<<1024, TH, 0, stream>>>(x, adj, wt, out, psum);
    bn_stats<<<C_SZ, 64, 0, stream>>>(psum, gamma, beta, mr);
    bn_apply<<<2048, 256, 0, stream>>>(out, mr);
}